// Round 3
// baseline (307.399 us; speedup 1.0000x reference)
//
#include <hip/hip_runtime.h>
#include <math.h>

#define Bsz   120
#define Nv    128
#define Ms    192            // checks per s (rows of Hz for s=0, Hx for s=1)
#define Tit   25
#define NT    192            // threads per block (3 waves); thread == check in B
#define ESLOT 5
#define EMAXS (NT * ESLOT)   // 960 padded edge slots per s (expected ~768)

// ws int layout per s: rp[193] | vp[129] | rcol[960] | echk[960] | veid[960]
#define O_RP    0
#define O_VP    193
#define O_RCOL  322
#define O_ECHK  1282
#define O_VEID  2242
#define SSTRIDE 3202
#define WS_PART (2 * SSTRIDE)   // float part[2][Bsz][Tit] = 6000 floats

// phi(x) = -log(tanh(x/2)) = ln2*(log2(1+u) - log2(1-u)), u = e^-x, clip [1e-6,30].
// Small-x: 1-u computed by series to kill cancellation (rel err <= ~4e-5).
__device__ __forceinline__ float phi_f(float x) {
  x = fminf(fmaxf(x, 1e-6f), 30.0f);
  const float u = __expf(-x);
  float den = 1.0f - u;
  if (x < 0.03125f) den = x * (1.0f - 0.5f * x + 0.16666667f * x * x);
  return 0.69314718f * (__log2f(1.0f + u) - __log2f(den));
}

// ---------------------------------------------------------------------------
// Setup: grid=2 (one block per s). Builds check CSR (rp/rcol/echk) and
// variable CSR (vp/veid) in ws. Deterministic, no atomics.
// ---------------------------------------------------------------------------
__global__ __launch_bounds__(NT) void setup_kernel(const float* __restrict__ Hx,
                                                   const float* __restrict__ Hz,
                                                   int* __restrict__ W) {
  const int s = blockIdx.x;
  int* rp   = W + s * SSTRIDE + O_RP;
  int* vp   = W + s * SSTRIDE + O_VP;
  int* rcol = W + s * SSTRIDE + O_RCOL;
  int* echk = W + s * SSTRIDE + O_ECHK;
  int* veid = W + s * SSTRIDE + O_VEID;
  const float* H = s ? Hx : Hz;            // Hs = stack([Hz, Hx])
  __shared__ int deg[Ms];
  __shared__ int vdeg[Nv];
  const int tid = threadIdx.x;

  {
    int cnt = 0;
    for (int n = 0; n < Nv; ++n) cnt += (H[tid * Nv + n] > 0.f) ? 1 : 0;
    deg[tid] = cnt;
  }
  __syncthreads();
  if (tid == 0) {
    int acc = 0;
    for (int c = 0; c < Ms; ++c) { rp[c] = acc; acc += deg[c]; }
    rp[Ms] = (acc <= EMAXS) ? acc : EMAXS;
  }
  __syncthreads();
  {
    int o = rp[tid];
    const int lim = (rp[tid + 1] <= EMAXS) ? rp[tid + 1] : EMAXS;
    for (int n = 0; n < Nv && o < lim; ++n)
      if (H[tid * Nv + n] > 0.f) { rcol[o] = n; echk[o] = tid; ++o; }
  }
  __syncthreads();
  const int E = rp[Ms];
  for (int e = E + tid; e < EMAXS; e += NT) echk[e] = Ms;   // dummy check id
  if (tid < Nv) {
    int cnt = 0;
    for (int e = 0; e < E; ++e) cnt += (rcol[e] == tid) ? 1 : 0;
    vdeg[tid] = cnt;
  }
  __syncthreads();
  if (tid == 0) {
    int acc = 0;
    for (int v = 0; v < Nv; ++v) { vp[v] = acc; acc += vdeg[v]; }
    vp[Nv] = acc;
  }
  __syncthreads();
  if (tid < Nv) {
    int o = vp[tid];
    for (int e = 0; e < E; ++e)
      if (rcol[e] == tid) veid[o++] = e;
  }
}

// ---------------------------------------------------------------------------
// Main: one block per (b, s). All state LDS-resident for 25 iterations.
// Phases: A edge-phi | B check reduce | C edge cn | D variable update
//         (loss of t-1 runs on wave 2 concurrently with D; corr dbuf'd).
// Writes per-iteration partial losses part[s][b][t] to ws.
// ---------------------------------------------------------------------------
__global__ __launch_bounds__(NT) void nbp_kernel(
    const float* __restrict__ errorx, const float* __restrict__ errorz,
    const float* __restrict__ ep0,
    const float* __restrict__ Gx, const float* __restrict__ Gz,
    const float* __restrict__ w_llr, const float* __restrict__ w_vn,
    const float* __restrict__ w_cn,
    int* __restrict__ W) {
  __shared__ float V[EMAXS];
  __shared__ float p[EMAXS];        // |phi| with V's sign folded (|p| >= 1e-30)
  __shared__ float cnm[EMAXS];
  __shared__ unsigned short echk[EMAXS];
  __shared__ unsigned short veid[EMAXS];
  __shared__ int rp[Ms + 1];
  __shared__ int vp[Nv + 1];
  __shared__ float psum[Ms + 1], tot[Ms + 1];
  __shared__ float errx[Nv], errz[Nv];
  __shared__ float gR[2][Nv];       // rows of Gx (s=0) or Gz (s=1)
  __shared__ float ssgn[Ms];
  __shared__ float corrbuf[2][Nv];  // t-parity double buffer
  __shared__ float wl[Tit], wvv[Tit], wc[Tit];
  __shared__ float plost[Tit];

  const int tid = threadIdx.x;
  const int bid = blockIdx.x;
  const int b = bid >> 1, s = bid & 1;
  const int* base   = W + s * SSTRIDE;
  const int* rp_g   = base + O_RP;
  const int* vp_g   = base + O_VP;
  const int* rcol_g = base + O_RCOL;
  const int* echk_g = base + O_ECHK;
  const int* veid_g = base + O_VEID;
  float* part = (float*)(W + WS_PART) + (s * Bsz + b) * Tit;

  const float ep   = ep0[0];
  const float a23  = (2.0f * ep) / 3.0f;
  const float llr0 = logf((1.0f - a23) / a23);

  // ---- init loads ----
  for (int i = tid; i <= Ms; i += NT) rp[i] = rp_g[i];
  if (tid <= Nv) vp[tid] = vp_g[tid];
  if (tid < Nv) {
    errx[tid] = errorx[b * Nv + tid];
    errz[tid] = errorz[b * Nv + tid];
  }
  {
    const float* G = s ? Gz : Gx;     // s=0: Gx·corrz ; s=1: Gz·corrx
    for (int i = tid; i < 2 * Nv; i += NT) gR[i >> 7][i & (Nv - 1)] = G[i];
  }
  if (tid < 3 * Tit) {
    if (tid < Tit)          wl[tid]           = w_llr[tid];
    else if (tid < 2 * Tit) wvv[tid - Tit]    = w_vn[tid - Tit];
    else                    wc[tid - 2 * Tit] = w_cn[tid - 2 * Tit];
  }
  if (tid == 0) { psum[Ms] = 0.f; tot[Ms] = 0.f; }
  __syncthreads();
  const int E = rp[Ms];

  // ---- edge arrays + V init + syndrome signs ----
  for (int e = tid; e < EMAXS; e += NT) {
    echk[e] = (unsigned short)echk_g[e];
    V[e] = (e < E) ? llr0 : 1.0f;       // benign dummy value
  }
  for (int e = tid; e < E; e += NT) veid[e] = (unsigned short)veid_g[e];
  {
    // s=0: synx = errorx @ Hz.T ; s=1: synz = errorz @ Hx.T
    const float* esyn = s ? errz : errx;
    int par = 0;
    for (int e = rp[tid]; e < rp[tid + 1]; ++e)
      par ^= (esyn[rcol_g[e]] > 0.5f) ? 1 : 0;
    ssgn[tid] = par ? -1.f : 1.f;
  }
  __syncthreads();

  // wave-2 loss: 2 dots of 128 (32 lanes x 4 each) + |sin|, result -> plost[tp]
  auto loss_step = [&](int tp) {
    const int lane = tid - 128;         // wave-relative lane 0..63
    const int g = lane >> 5, q = lane & 31;
    const float* cr = corrbuf[tp & 1];
    float a = 0.f;
#pragma unroll
    for (int j = 0; j < 4; ++j) a += gR[g][q + 32 * j] * cr[q + 32 * j];
    a += __shfl_xor(a, 1);
    a += __shfl_xor(a, 2);
    a += __shfl_xor(a, 4);
    a += __shfl_xor(a, 8);
    a += __shfl_xor(a, 16);
    const float sv = fabsf(__sinf(1.57079632679f * a));
    const float lt = __shfl(sv, 0) + __shfl(sv, 32);
    if (lane == 0) plost[tp] = lt;
  };

  for (int t = 0; t < Tit; ++t) {
    // ---- A: edge-parallel phi (5 fixed slots, unrolled -> ILP) ----
#pragma unroll
    for (int k = 0; k < ESLOT; ++k) {
      const int e = tid + k * NT;
      const float v = V[e];
      float pv = phi_f(fabsf(v));
      pv = fmaxf(pv, 1e-30f);           // keep sign representable
      p[e] = (v < 0.f) ? -pv : pv;
    }
    __syncthreads();
    // ---- B: per-check psum / signed total (thread == check) ----
    {
      const int beg = rp[tid], end = rp[tid + 1];
      float sum = 0.f;
      unsigned par = 0;
      for (int e = beg; e < end; ++e) {
        const float ps = p[e];
        par ^= (__float_as_uint(ps) >> 31);
        sum += fabsf(ps);
      }
      psum[tid] = sum;
      tot[tid] = ((par & 1u) ? -ssgn[tid] : ssgn[tid]) * wc[t];
    }
    __syncthreads();
    // ---- C: edge-parallel cn messages ----
#pragma unroll
    for (int k = 0; k < ESLOT; ++k) {
      const int e = tid + k * NT;
      const int c = echk[e];
      const float ps = p[e];
      const float sg = (__float_as_uint(ps) >> 31) ? -1.f : 1.f;
      cnm[e] = tot[c] * sg * phi_f(psum[c] - fabsf(ps));
    }
    __syncthreads();
    // ---- D: variable update (threads 0..127) || loss(t-1) (wave 2) ----
    if (tid < Nv) {
      const int beg = vp[tid], end = vp[tid + 1];
      float cs = 0.f;
      for (int k = beg; k < end; ++k) cs += cnm[veid[k]];
      const float bse = wl[t] * llr0;
      const float wvt = wvv[t];
      for (int k = beg; k < end; ++k) {
        const int e = veid[k];
        V[e] = bse + wvt * (cs - cnm[e]);
      }
      const float gamma = bse + cs;
      const float prob = 1.0f / (1.0f + __expf(gamma));  // sigmoid(-gamma)
      // s=0: corrz = sel(errz, 1-pX, pX) ; s=1: corrx = sel(errx, 1-pZ, pZ)
      const float ec = (s ? errx : errz)[tid];
      corrbuf[t & 1][tid] = (ec > 0.5f) ? 1.0f - prob : prob;
    } else if (tid >= 128 && t > 0) {
      loss_step(t - 1);
    }
    __syncthreads();
  }
  if (tid >= 128) loss_step(Tit - 1);
  __syncthreads();
  if (tid < Tit) part[tid] = plost[tid];
}

// ---------------------------------------------------------------------------
// Final combine: loss_t[b] = partA + partB; mean_b(sum_t), mean_b(min_t).
// One block, 128 threads; deterministic.
// ---------------------------------------------------------------------------
__global__ __launch_bounds__(128) void reduce_kernel(const int* __restrict__ W,
                                                     float* __restrict__ out) {
  const float* part = (const float*)(W + WS_PART);
  __shared__ float wsum[2], wmin[2];
  const int tid = threadIdx.x;
  float sm = 0.f, mn = 0.f;
  if (tid < Bsz) {
    const float* pa = part + tid * Tit;               // s=0
    const float* pb = part + (Bsz + tid) * Tit;       // s=1
    float acc = 0.f, mloc = 3.0e38f;
    for (int t = 0; t < Tit; ++t) {
      const float lt = pa[t] + pb[t];
      acc += lt;
      mloc = fminf(mloc, lt);
    }
    sm = acc;
    mn = mloc;
  }
  for (int off = 32; off; off >>= 1) {   // sum per-b values across lanes
    sm += __shfl_down(sm, off);
    mn += __shfl_down(mn, off);
  }
  const int w = tid >> 6;
  if ((tid & 63) == 0) { wsum[w] = sm; wmin[w] = mn; }
  __syncthreads();
  if (tid == 0) {
    out[0] = (wsum[0] + wsum[1]) * (1.0f / Bsz);
    out[1] = (wmin[0] + wmin[1]) * (1.0f / Bsz);
  }
}

extern "C" void kernel_launch(void* const* d_in, const int* in_sizes, int n_in,
                              void* d_out, int out_size, void* d_ws, size_t ws_size,
                              hipStream_t stream) {
  const float* errorx = (const float*)d_in[0];
  const float* errorz = (const float*)d_in[1];
  const float* ep0    = (const float*)d_in[2];
  const float* Hx     = (const float*)d_in[3];
  const float* Hz     = (const float*)d_in[4];
  const float* Gx     = (const float*)d_in[5];
  const float* Gz     = (const float*)d_in[6];
  const float* wllr   = (const float*)d_in[7];
  const float* wvn    = (const float*)d_in[8];
  const float* wcn    = (const float*)d_in[9];
  float* out = (float*)d_out;
  int* W = (int*)d_ws;

  hipLaunchKernelGGL(setup_kernel, dim3(2), dim3(NT), 0, stream, Hx, Hz, W);
  hipLaunchKernelGGL(nbp_kernel, dim3(2 * Bsz), dim3(NT), 0, stream,
                     errorx, errorz, ep0, Gx, Gz, wllr, wvn, wcn, W);
  hipLaunchKernelGGL(reduce_kernel, dim3(1), dim3(128), 0, stream, W, out);
}